// Round 1
// baseline (164.605 us; speedup 1.0000x reference)
//
#include <hip/hip_runtime.h>
#include <stdint.h>

// DenseTNT postprocess: per batch row, greedy goal-NMS (2 m threshold, strict <)
// over score-descending order, select 6 modes, gather trajs + scores.
//
// argsort+scan greedy NMS == 6 rounds of masked argmax ("best surviving
// candidate") -> no sort needed. Tie-break matches stable argsort:
// equal score -> lower original index wins (encoded in the u64 key).
//
// R3 (latency-path restructure; kernel is latency-bound, ~6 MB traffic):
//  - block 256 (16 cand/thread): barrier cohort 16 -> 4 waves.
//  - ONE barrier per round (was 2): goals staged once in LDS as a read-only
//    table; every thread fetches goal[winner] itself (uniform addr =
//    broadcast read). No owner-write round trip.
//  - u64 LDS atomicMax (CAS loop on gfx950 DS) removed: per-wave shfl
//    reduce + per-round 4-slot LDS array (indexed by m -> no reset, no
//    extra barrier, no write-after-read race with stragglers).
//  - score keys hoisted (static); suppression zeroes the key; winner score
//    decoded from the key in the epilogue (no LDS tables, no epilogue
//    barrier; uniform select chain keeps arrays statically indexed).

namespace {
constexpr int kB      = 128;
constexpr int kN      = 4096;
constexpr int kSteps  = 30;
constexpr int kModes  = 6;
constexpr int kTPB    = 256;
constexpr int kWaves  = kTPB / 64;        // 4
constexpr int kVec    = kN / 4 / kTPB;    // 4 float4 loads per thread per array
constexpr int kPer    = kN / kTPB;        // 16 candidates per thread
constexpr int kOutT   = kModes * 2 * kSteps;  // 360 traj floats per batch
constexpr float kThresh2 = 4.0f;          // THRESHOLD^2
}

// Monotone map float -> uint32 (preserves total order for all finite floats).
__device__ __forceinline__ unsigned int order_key(float f) {
    unsigned int u = __float_as_uint(f);
    return (u & 0x80000000u) ? ~u : (u | 0x80000000u);
}

// Inverse of order_key (recover score from key high word).
__device__ __forceinline__ float decode_score(unsigned long long key) {
    unsigned int hk = (unsigned int)(key >> 32);
    unsigned int u  = (hk & 0x80000000u) ? (hk & 0x7FFFFFFFu) : ~hk;
    return __uint_as_float(u);
}

__device__ __forceinline__ unsigned long long shfl_down_u64(unsigned long long v, int off) {
    unsigned int lo = (unsigned int)(v & 0xFFFFFFFFull);
    unsigned int hi = (unsigned int)(v >> 32);
    lo = __shfl_down(lo, off, 64);
    hi = __shfl_down(hi, off, 64);
    return (((unsigned long long)hi) << 32) | (unsigned long long)lo;
}

__global__ __launch_bounds__(kTPB)
void densetnt_nms_kernel(const float* __restrict__ scores,   // [B, N]
                         const float* __restrict__ trajs,    // [B, 2*P, N]
                         const float* __restrict__ goals,    // [B, 2, N]
                         float* __restrict__ out) {          // [B*6*60] trajs, then [B*6] scores
    const int b    = blockIdx.x;
    const int tid  = threadIdx.x;
    const int lane = tid & 63;
    const int wid  = tid >> 6;

    __shared__ __align__(16) float s_gx[kN];                 // goal table (read-only after stage)
    __shared__ __align__(16) float s_gy[kN];
    __shared__ unsigned long long s_wbest[kModes][kWaves];   // per-round slots: no reset needed

    const float4* sc4 = (const float4*)(scores + (size_t)b * kN);
    const float4* gx4 = (const float4*)(goals  + (size_t)b * 2 * kN);
    const float4* gy4 = (const float4*)(goals  + (size_t)b * 2 * kN + kN);

    // Candidate ownership: thread owns idx = 4*(tid + j*256) + c, j=0..3, c=0..3
    // (coalesced float4 loads; original index is encoded in the key, so the
    // ownership mapping is irrelevant to correctness).
    unsigned long long key[kPer];   // 0 == suppressed/taken (impossible for finite scores)
    float gxr[kPer], gyr[kPer];

    #pragma unroll
    for (int j = 0; j < kVec; ++j) {
        const int v4 = tid + j * kTPB;          // float4 index within the row
        float4 vs = sc4[v4];
        float4 vx = gx4[v4];
        float4 vy = gy4[v4];
        ((float4*)s_gx)[v4] = vx;               // contiguous b128 LDS writes: conflict-free
        ((float4*)s_gy)[v4] = vy;
        const float fs[4] = {vs.x, vs.y, vs.z, vs.w};
        const float fx[4] = {vx.x, vx.y, vx.z, vx.w};
        const float fy[4] = {vy.x, vy.y, vy.z, vy.w};
        #pragma unroll
        for (int c = 0; c < 4; ++c) {
            const unsigned int idx = (unsigned int)(4 * v4 + c);
            key[j * 4 + c] = (((unsigned long long)order_key(fs[c])) << 32)
                           | (unsigned long long)(0xFFFFFFFFu - idx);
            gxr[j * 4 + c] = fx[c];
            gyr[j * 4 + c] = fy[c];
        }
    }

    unsigned long long sk[kModes];  // block-uniform winner key per round

    #pragma unroll
    for (int m = 0; m < kModes; ++m) {
        // Local masked argmax (suppressed keys are 0).
        unsigned long long best = key[0];
        #pragma unroll
        for (int c = 1; c < kPer; ++c) best = key[c] > best ? key[c] : best;
        // Wave reduce (6 levels).
        #pragma unroll
        for (int off = 32; off > 0; off >>= 1) {
            unsigned long long o = shfl_down_u64(best, off);
            best = o > best ? o : best;
        }
        if (lane == 0) s_wbest[m][wid] = best;
        __syncthreads();    // for m==0 this also covers the s_gx/s_gy staging

        // Block max: 4 broadcast LDS reads, computed redundantly by all threads.
        unsigned long long k = s_wbest[m][0];
        #pragma unroll
        for (int w = 1; w < kWaves; ++w) {
            unsigned long long o = s_wbest[m][w];
            k = o > k ? o : k;
        }
        sk[m] = k;

        if (k != 0ULL) {
            const int idx = (int)(0xFFFFFFFFu - (unsigned int)(k & 0xFFFFFFFFull));
            const float wx = s_gx[idx];   // uniform address -> broadcast, no conflict
            const float wy = s_gy[idx];
            #pragma unroll
            for (int c = 0; c < kPer; ++c) {
                const float dx = gxr[c] - wx;
                const float dy = gyr[c] - wy;
                if (dx * dx + dy * dy < kThresh2) key[c] = 0ULL;  // winner kills itself too (d=0)
            }
        }
        // k==0: survivors only shrink -> all later rounds empty; fallback below.
        // Note: no second barrier. Next round's leader writes go to slot [m+1],
        // disjoint from any straggler still reading slot [m] / the goal table.
    }

    // Unfilled slots fall back to round-0 winner (== sorted index 0; always valid).
    #pragma unroll
    for (int m = 1; m < kModes; ++m) sk[m] = sk[m] ? sk[m] : sk[0];

    // Gather trajectories: out[b,m,pc] = trajs[b, pc, sel_idx[m]], pc in [0,60).
    const float* tb   = trajs + (size_t)b * (2 * kSteps) * kN;
    float*       outt = out   + (size_t)b * kOutT;
    for (int i = tid; i < kOutT; i += kTPB) {
        const int m  = i / (2 * kSteps);
        const int pc = i - m * (2 * kSteps);
        // Statically-indexed select chain (uniform values; avoids scratch spill).
        unsigned long long k = sk[0];
        #pragma unroll
        for (int mm = 1; mm < kModes; ++mm) k = (m == mm) ? sk[mm] : k;
        const int idx = (int)(0xFFFFFFFFu - (unsigned int)(k & 0xFFFFFFFFull));
        outt[i] = tb[(size_t)pc * kN + idx];
    }
    if (tid < kModes) {
        unsigned long long k = sk[0];
        #pragma unroll
        for (int mm = 1; mm < kModes; ++mm) k = (tid == mm) ? sk[mm] : k;
        out[(size_t)kB * kModes * 2 * kSteps + (size_t)b * kModes + tid] = decode_score(k);
    }
}

extern "C" void kernel_launch(void* const* d_in, const int* in_sizes, int n_in,
                              void* d_out, int out_size, void* d_ws, size_t ws_size,
                              hipStream_t stream) {
    const float* scores = (const float*)d_in[0];  // goals_scores [128, 4096]
    const float* trajs  = (const float*)d_in[1];  // traj_preds  [128, 60, 4096]
    const float* goals  = (const float*)d_in[2];  // pred_goals  [128, 2, 4096]
    float* out = (float*)d_out;
    densetnt_nms_kernel<<<kB, kTPB, 0, stream>>>(scores, trajs, goals, out);
}